// Round 2
// baseline (247.897 us; speedup 1.0000x reference)
//
#include <hip/hip_runtime.h>
#include <math.h>

#define NROWS 16384
#define NCOLS 4096

// ---------------------------------------------------------------------------
// Stage 1: per-(row-chunk, column) partial sums of the 5 stats.
// grid = (NCOLS/512, R) = (8, 256) = 2048 blocks -> 8 blocks/CU, full
// occupancy for latency hiding. Each thread owns 2 consecutive columns
// (float2, 8 B/lane coalesced); loops over its 64-row chunk.
// partial layout: [gy][5][NCOLS] floats (size depends only on R).
// ---------------------------------------------------------------------------
__global__ __launch_bounds__(256) void stats_partial_kernel(
    const float* __restrict__ preds,
    const float* __restrict__ targets,
    float* __restrict__ partial,
    int rows_per_chunk)
{
    const int col = (blockIdx.x * 256 + threadIdx.x) * 2;
    const int r0  = blockIdx.y * rows_per_chunk;
    int r1 = r0 + rows_per_chunk;
    if (r1 > NROWS) r1 = NROWS;

    float2 sp  = {0.f, 0.f};
    float2 st  = {0.f, 0.f};
    float2 spp = {0.f, 0.f};
    float2 stt = {0.f, 0.f};
    float2 spt = {0.f, 0.f};

    const float* __restrict__ pp = preds   + (size_t)r0 * NCOLS + col;
    const float* __restrict__ tp = targets + (size_t)r0 * NCOLS + col;

    #pragma unroll 8
    for (int r = r0; r < r1; ++r) {
        float2 p = *(const float2*)pp;
        float2 t = *(const float2*)tp;
        sp.x  += p.x;        sp.y  += p.y;
        st.x  += t.x;        st.y  += t.y;
        spp.x += p.x * p.x;  spp.y += p.y * p.y;
        stt.x += t.x * t.x;  stt.y += t.y * t.y;
        spt.x += p.x * t.x;  spt.y += p.y * t.y;
        pp += NCOLS;
        tp += NCOLS;
    }

    float* base = partial + ((size_t)blockIdx.y * 5) * NCOLS + col;
    *(float2*)(base + 0 * NCOLS) = sp;
    *(float2*)(base + 1 * NCOLS) = st;
    *(float2*)(base + 2 * NCOLS) = spp;
    *(float2*)(base + 3 * NCOLS) = stt;
    *(float2*)(base + 4 * NCOLS) = spt;
}

// ---------------------------------------------------------------------------
// Stage 2: reduce partials over chunks, compute per-column pcc + cos, reduce
// across columns, accumulate affine-transformed result into d_out.
// grid = NCOLS/256 = 16 blocks, one column per thread.
// Each block adds (2/nblocks - blocksum/NCOLS); total = 2 - mean(pcc+cos).
// ---------------------------------------------------------------------------
__global__ __launch_bounds__(256) void finalize_kernel(
    const float* __restrict__ partial,
    int R,
    float* __restrict__ out)
{
    const int col = blockIdx.x * 256 + threadIdx.x;

    float s0 = 0.f, s1 = 0.f, s2 = 0.f, s3 = 0.f, s4 = 0.f;  // sp, st, spp, stt, spt
    #pragma unroll 4
    for (int gy = 0; gy < R; ++gy) {
        const float* base = partial + ((size_t)gy * 5) * NCOLS + col;
        s0 += base[0 * NCOLS];
        s1 += base[1 * NCOLS];
        s2 += base[2 * NCOLS];
        s3 += base[3 * NCOLS];
        s4 += base[4 * NCOLS];
    }

    const float invN = 1.0f / (float)NROWS;
    float mu_p = s0 * invN;
    float mu_t = s1 * invN;
    float var_p = fmaxf(s2 * invN - mu_p * mu_p, 0.f);
    float var_t = fmaxf(s3 * invN - mu_t * mu_t, 0.f);
    float cov   = s4 * invN - mu_p * mu_t;

    float denom = sqrtf(var_p * var_t);
    float pcc = (denom > 0.f) ? (cov / denom) : 0.f;   // NaN -> 0 semantics

    float np_ = fmaxf(sqrtf(s2), 1e-8f);
    float nt_ = fmaxf(sqrtf(s3), 1e-8f);
    float cs  = s4 / (np_ * nt_);

    float v = pcc + cs;

    // wave64 shuffle reduce
    for (int off = 32; off > 0; off >>= 1)
        v += __shfl_down(v, off, 64);

    __shared__ float wsum[4];
    const int lane = threadIdx.x & 63;
    const int wid  = threadIdx.x >> 6;
    if (lane == 0) wsum[wid] = v;
    __syncthreads();

    if (threadIdx.x == 0) {
        float bsum = wsum[0] + wsum[1] + wsum[2] + wsum[3];
        float contrib = 2.0f / (float)gridDim.x - bsum / (float)NCOLS;
        atomicAdd(out, contrib);
    }
}

extern "C" void kernel_launch(void* const* d_in, const int* in_sizes, int n_in,
                              void* d_out, int out_size, void* d_ws, size_t ws_size,
                              hipStream_t stream) {
    const float* preds   = (const float*)d_in[0];
    const float* targets = (const float*)d_in[1];
    float* out = (float*)d_out;
    float* partial = (float*)d_ws;

    // Pick row-chunk count R to fit workspace: need R*5*NCOLS*4 bytes.
    // R=256 -> 20 MB. Round 1 proved ws_size >= 10 MB; keep the fallback.
    int R = 256;
    size_t per_chunk_bytes = (size_t)5 * NCOLS * sizeof(float);
    if ((size_t)R * per_chunk_bytes > ws_size) {
        R = (int)(ws_size / per_chunk_bytes);
        if (R < 1) R = 1;
    }
    int rows_per_chunk = (NROWS + R - 1) / R;
    // recompute R so there are no empty chunks
    R = (NROWS + rows_per_chunk - 1) / rows_per_chunk;

    hipMemsetAsync(d_out, 0, sizeof(float), stream);

    dim3 grid1(NCOLS / (256 * 2), R);
    stats_partial_kernel<<<grid1, 256, 0, stream>>>(preds, targets, partial, rows_per_chunk);

    finalize_kernel<<<NCOLS / 256, 256, 0, stream>>>(partial, R, out);
}

// Round 3
// 138.704 us; speedup vs baseline: 1.7872x; 1.7872x over previous
//
#include <hip/hip_runtime.h>
#include <math.h>

#define NROWS 16384
#define NCOLS 4096

// ---------------------------------------------------------------------------
// Stage 1: per-(row-chunk) partial sums of the 5 stats for ALL columns.
// One 1024-thread block spans the full 4096-col row: thread t owns cols
// 4t..4t+3 (float4 -> 16 B/lane, the whole block reads each 16 KB row
// contiguously). Each block streams rows r0..r0+31 -> a contiguous 2 MB
// region of each input. grid = R = 512 blocks = 2 blocks/CU (32 waves/CU).
// partial layout: [gy][5][NCOLS] floats.
// ---------------------------------------------------------------------------
__global__ __launch_bounds__(1024, 8) void stats_partial_kernel(
    const float* __restrict__ preds,
    const float* __restrict__ targets,
    float* __restrict__ partial,
    int rows_per_chunk)
{
    const int col = threadIdx.x * 4;
    const int r0  = blockIdx.x * rows_per_chunk;
    int r1 = r0 + rows_per_chunk;
    if (r1 > NROWS) r1 = NROWS;

    float4 sp  = {0.f, 0.f, 0.f, 0.f};
    float4 st  = {0.f, 0.f, 0.f, 0.f};
    float4 spp = {0.f, 0.f, 0.f, 0.f};
    float4 stt = {0.f, 0.f, 0.f, 0.f};
    float4 spt = {0.f, 0.f, 0.f, 0.f};

    const float* __restrict__ pp = preds   + (size_t)r0 * NCOLS + col;
    const float* __restrict__ tp = targets + (size_t)r0 * NCOLS + col;

    #pragma unroll 4
    for (int r = r0; r < r1; ++r) {
        float4 p = *(const float4*)pp;
        float4 t = *(const float4*)tp;
        sp.x  += p.x;        sp.y  += p.y;        sp.z  += p.z;        sp.w  += p.w;
        st.x  += t.x;        st.y  += t.y;        st.z  += t.z;        st.w  += t.w;
        spp.x += p.x * p.x;  spp.y += p.y * p.y;  spp.z += p.z * p.z;  spp.w += p.w * p.w;
        stt.x += t.x * t.x;  stt.y += t.y * t.y;  stt.z += t.z * t.z;  stt.w += t.w * t.w;
        spt.x += p.x * t.x;  spt.y += p.y * t.y;  spt.z += p.z * t.z;  spt.w += p.w * t.w;
        pp += NCOLS;
        tp += NCOLS;
    }

    float* base = partial + ((size_t)blockIdx.x * 5) * NCOLS + col;
    *(float4*)(base + 0 * NCOLS) = sp;
    *(float4*)(base + 1 * NCOLS) = st;
    *(float4*)(base + 2 * NCOLS) = spp;
    *(float4*)(base + 3 * NCOLS) = stt;
    *(float4*)(base + 4 * NCOLS) = spt;
}

// ---------------------------------------------------------------------------
// Stage 2: reduce partials over chunks + per-column pcc/cos + per-block sum.
// grid = NCOLS/16 = 256 blocks, 256 threads = 16 cols x 16 chunk-lanes.
// Writes blocksum[b] = sum over the block's 16 columns of (pcc + cos).
// Deterministic: fixed loop order, fixed LDS tree, no atomics.
// ---------------------------------------------------------------------------
__global__ __launch_bounds__(256) void reduce_cols_kernel(
    const float* __restrict__ partial,
    int R,
    float* __restrict__ blocksum)
{
    const int ci  = threadIdx.x & 15;   // column within block
    const int gi  = threadIdx.x >> 4;   // chunk-lane 0..15
    const int col = blockIdx.x * 16 + ci;

    float s[5] = {0.f, 0.f, 0.f, 0.f, 0.f};
    for (int gy = gi; gy < R; gy += 16) {
        const float* base = partial + ((size_t)gy * 5) * NCOLS + col;
        #pragma unroll
        for (int k = 0; k < 5; ++k) s[k] += base[k * NCOLS];
    }

    __shared__ float red[256][5];
    #pragma unroll
    for (int k = 0; k < 5; ++k) red[threadIdx.x][k] = s[k];
    __syncthreads();

    __shared__ float colval[16];
    if (threadIdx.x < 16) {
        float t[5] = {0.f, 0.f, 0.f, 0.f, 0.f};
        for (int g = 0; g < 16; ++g) {
            #pragma unroll
            for (int k = 0; k < 5; ++k) t[k] += red[threadIdx.x + 16 * g][k];
        }
        // t = {sum_p, sum_t, sum_pp, sum_tt, sum_pt}
        const float invN = 1.0f / (float)NROWS;
        float mu_p = t[0] * invN;
        float mu_t = t[1] * invN;
        float var_p = fmaxf(t[2] * invN - mu_p * mu_p, 0.f);
        float var_t = fmaxf(t[3] * invN - mu_t * mu_t, 0.f);
        float cov   = t[4] * invN - mu_p * mu_t;

        float denom = sqrtf(var_p * var_t);
        float pcc = (denom > 0.f) ? (cov / denom) : 0.f;  // NaN -> 0 semantics

        float np_ = fmaxf(sqrtf(t[2]), 1e-8f);
        float nt_ = fmaxf(sqrtf(t[3]), 1e-8f);
        float cs  = t[4] / (np_ * nt_);

        colval[threadIdx.x] = pcc + cs;
    }
    __syncthreads();

    if (threadIdx.x == 0) {
        float b = 0.f;
        #pragma unroll
        for (int i = 0; i < 16; ++i) b += colval[i];
        blocksum[blockIdx.x] = b;
    }
}

// ---------------------------------------------------------------------------
// Stage 3: single block folds the 256 block sums into the scalar output.
// out = 2 - (sum of all per-column (pcc+cos)) / NCOLS
// ---------------------------------------------------------------------------
__global__ __launch_bounds__(256) void final_reduce_kernel(
    const float* __restrict__ blocksum,
    float* __restrict__ out)
{
    float v = blocksum[threadIdx.x];
    for (int off = 32; off > 0; off >>= 1)
        v += __shfl_down(v, off, 64);

    __shared__ float w[4];
    const int lane = threadIdx.x & 63;
    const int wid  = threadIdx.x >> 6;
    if (lane == 0) w[wid] = v;
    __syncthreads();

    if (threadIdx.x == 0)
        out[0] = 2.0f - (w[0] + w[1] + w[2] + w[3]) / (float)NCOLS;
}

extern "C" void kernel_launch(void* const* d_in, const int* in_sizes, int n_in,
                              void* d_out, int out_size, void* d_ws, size_t ws_size,
                              hipStream_t stream) {
    const float* preds   = (const float*)d_in[0];
    const float* targets = (const float*)d_in[1];
    float* out = (float*)d_out;
    float* partial = (float*)d_ws;

    // R row-chunks; need R*5*NCOLS*4 B + 256*4 B of workspace.
    // R=512 -> ~40 MB (ws observed ~1 GB in round 2; keep fallback anyway).
    int R = 512;
    size_t per_chunk_bytes = (size_t)5 * NCOLS * sizeof(float);
    size_t tail_bytes = 256 * sizeof(float);
    if ((size_t)R * per_chunk_bytes + tail_bytes > ws_size) {
        R = (int)((ws_size - tail_bytes) / per_chunk_bytes);
        if (R < 1) R = 1;
    }
    int rows_per_chunk = (NROWS + R - 1) / R;
    R = (NROWS + rows_per_chunk - 1) / rows_per_chunk;   // no empty chunks

    float* blocksum = partial + (size_t)R * 5 * NCOLS;

    stats_partial_kernel<<<R, 1024, 0, stream>>>(preds, targets, partial, rows_per_chunk);
    reduce_cols_kernel<<<NCOLS / 16, 256, 0, stream>>>(partial, R, blocksum);
    final_reduce_kernel<<<1, 256, 0, stream>>>(blocksum, out);
}